// Round 3
// baseline (1472.305 us; speedup 1.0000x reference)
//
#include <hip/hip_runtime.h>

// Fused entmax(alpha=1.3) attention, fp32. B=16, N=2048, D=64.
// R3: spill fix — tile loops fully unrolled so s[2][32] has only compile-time
// indices (R2's runtime-t indexing demoted it to scratch: VGPR=72, +720 MB
// spill writes). PV now also tiled through LDS (V shared across the wave's
// 2 rows; p via 4 KB per-wave LDS hop). Non-temporal attn stores keep the
// 268 MB stream out of L2.

#define NBATCH 16
#define NSEQ   2048
#define DHEAD  64
#define OUT_OFF (NBATCH * NSEQ * DHEAD)   // out first, attn second
#define INV_A    3.3333333f               // 1/(alpha-1)
#define INV_A_M1 2.3333333f               // INV_A - 1
#define TK    128                         // tile rows (K and V phases)
#define PADK  68                          // LDS row stride: 272 B, 16B-aligned
#define NTILE (NSEQ / TK)                 // 16

__device__ __forceinline__ float fast_log2(float x) { return __builtin_amdgcn_logf(x); }
__device__ __forceinline__ float fast_exp2(float x) { return __builtin_amdgcn_exp2f(x); }

__global__ __launch_bounds__(256) void entmax_attn_kernel(
    const float* __restrict__ Q, const float* __restrict__ K,
    const float* __restrict__ V, float* __restrict__ Out)
{
    __shared__ __align__(16) float smem[TK * PADK];     // K tile, then V tile
    __shared__ __align__(16) float q_lds[8][DHEAD];
    __shared__ __align__(16) float p_tile[4][2][TK];    // per-wave p hop for PV

    const int tid  = threadIdx.x;
    const int w    = tid >> 6;        // wave 0..3
    const int lane = tid & 63;

    // XCD pinning: batch b -> XCD b%8 (K/V of a batch L2-resident)
    const int i   = blockIdx.x;       // 0..4095
    const int xcd = i & 7;
    const int j2  = i >> 3;
    const int b   = xcd + 8 * (j2 & 1);
    const int rb  = j2 >> 1;          // 0..255
    const int n0  = rb * 8;           // block covers q rows n0..n0+7

    const float* Kb = K + (size_t)b * NSEQ * DHEAD;
    const float* Vb = V + (size_t)b * NSEQ * DHEAD;

    // stage the block's 8 q rows
    if (tid < 128) {
        const int r = tid >> 4, g = tid & 15;
        ((float4*)q_lds[r])[g] =
            ((const float4*)(Q + ((size_t)b * NSEQ + (size_t)(n0 + r)) * DHEAD))[g];
    }

    // s[r][j] = score of q-row (n0+2w+r) vs key m = j*64 + lane.
    // ALL indexing below is compile-time -> stays in VGPRs.
    float s[2][32];

    const float* q0p = q_lds[2 * w + 0];
    const float* q1p = q_lds[2 * w + 1];

    // ---------------- phase 1: QK^T, K tiled through LDS ----------------
    #pragma unroll
    for (int t = 0; t < NTILE; ++t) {
        __syncthreads();   // prev tile consumed (t=0: also covers q staging)
        #pragma unroll
        for (int rep = 0; rep < 8; ++rep) {
            const int f = tid + rep * 256;
            const int m = f >> 4, g = f & 15;
            const float4 kv = ((const float4*)(Kb + (size_t)(t * TK + m) * DHEAD))[g];
            *(float4*)&smem[m * PADK + 4 * g] = kv;
        }
        __syncthreads();

        float a00 = 0.f, a01 = 0.f, a10 = 0.f, a11 = 0.f;
        #pragma unroll 1   // rolled: q re-read from LDS each g (no 128-reg hoist)
        for (int g = 0; g < 16; ++g) {
            const float4 k0 = *(const float4*)&smem[lane * PADK + 4 * g];        // m = t*128+lane
            const float4 k1 = *(const float4*)&smem[(64 + lane) * PADK + 4 * g]; // m = t*128+64+lane
            const float4 qa = *(const float4*)&q0p[4 * g];   // uniform-addr broadcast
            const float4 qb = *(const float4*)&q1p[4 * g];
            a00 += qa.x * k0.x + qa.y * k0.y + qa.z * k0.z + qa.w * k0.w;
            a01 += qa.x * k1.x + qa.y * k1.y + qa.z * k1.z + qa.w * k1.w;
            a10 += qb.x * k0.x + qb.y * k0.y + qb.z * k0.z + qb.w * k0.w;
            a11 += qb.x * k1.x + qb.y * k1.y + qb.z * k1.z + qb.w * k1.w;
        }
        s[0][2 * t]     = a00 * 0.125f;
        s[0][2 * t + 1] = a01 * 0.125f;
        s[1][2 * t]     = a10 * 0.125f;
        s[1][2 * t + 1] = a11 * 0.125f;
    }

    // ---------------- phase 2: entmax per q-row ----------------
    #pragma unroll
    for (int r = 0; r < 2; ++r) {
        float* sr = s[r];
        const int n = n0 + 2 * w + r;

        float mx = sr[0];
        #pragma unroll
        for (int j = 1; j < 32; ++j) mx = fmaxf(mx, sr[j]);
        #pragma unroll
        for (int off = 32; off >= 1; off >>= 1) mx = fmaxf(mx, __shfl_xor(mx, off, 64));
        #pragma unroll
        for (int j = 0; j < 32; ++j) sr[j] -= mx;

        // bisection: root of sum(max(x-tau,0)^INV_A) = 1 in [-1, -1e-6]
        float lo = -1.0f, hi = -1e-6f;
        #pragma unroll 1
        for (int it = 0; it < 12; ++it) {
            const float tau = 0.5f * (lo + hi);
            float S = 0.f;
            #pragma unroll
            for (int j = 0; j < 32; ++j) {
                const float t = sr[j] - tau;
                const float p = fast_exp2(INV_A * fast_log2(t));
                S += (t > 0.f) ? p : 0.f;
            }
            #pragma unroll
            for (int off = 32; off >= 1; off >>= 1) S += __shfl_xor(S, off, 64);
            if (S > 1.f) lo = tau; else hi = tau;   // uniform across wave
        }

        // Newton polish from left bracket (clamped, monotone-safe)
        float tau = lo;
        #pragma unroll 1
        for (int it = 0; it < 3; ++it) {
            float S1 = 0.f, S2 = 0.f;
            #pragma unroll
            for (int j = 0; j < 32; ++j) {
                const float t  = sr[j] - tau;
                const float l2 = fast_log2(t);
                const float p  = fast_exp2(INV_A * l2);
                const float pd = fast_exp2(INV_A_M1 * l2);
                const bool pos = (t > 0.f);
                S1 += pos ? p  : 0.f;
                S2 += pos ? pd : 0.f;
            }
            #pragma unroll
            for (int off = 32; off >= 1; off >>= 1) {
                S1 += __shfl_xor(S1, off, 64);
                S2 += __shfl_xor(S2, off, 64);
            }
            tau += (S1 - 1.f) / (INV_A * S2);
            tau = fmaxf(fminf(tau, hi), lo);
        }

        // final p + sum
        float S = 0.f;
        #pragma unroll
        for (int j = 0; j < 32; ++j) {
            const float t = sr[j] - tau;
            const float p = (t > 0.f) ? fast_exp2(INV_A * fast_log2(t)) : 0.f;
            sr[j] = p;
            S += p;
        }
        #pragma unroll
        for (int off = 32; off >= 1; off >>= 1) S += __shfl_xor(S, off, 64);
        const float rnorm = 1.f / (S + 1e-12f);

        // normalize in regs + non-temporal attn write (keep 268 MB out of L2)
        float* attn_row = Out + OUT_OFF + ((size_t)b * NSEQ + n) * NSEQ;
        #pragma unroll
        for (int j = 0; j < 32; ++j) {
            const float pv = sr[j] * rnorm;
            sr[j] = pv;
            __builtin_nontemporal_store(pv, &attn_row[j * 64 + lane]);
        }
    }

    // ---------------- phase 3: PV, V tiled through LDS ----------------
    const int msub = lane >> 4;
    const int d4   = lane & 15;
    float4 acc0 = make_float4(0.f, 0.f, 0.f, 0.f);
    float4 acc1 = make_float4(0.f, 0.f, 0.f, 0.f);

    #pragma unroll
    for (int t = 0; t < NTILE; ++t) {
        __syncthreads();   // K/V tile region free
        #pragma unroll
        for (int rep = 0; rep < 8; ++rep) {
            const int f = tid + rep * 256;
            const int m = f >> 4, g = f & 15;
            const float4 vv = ((const float4*)(Vb + (size_t)(t * TK + m) * DHEAD))[g];
            *(float4*)&smem[m * PADK + 4 * g] = vv;
        }
        // p hop: lane owns m = 128t + lane and 128t + 64 + lane (same-wave RAW)
        p_tile[w][0][lane]      = s[0][2 * t];
        p_tile[w][0][64 + lane] = s[0][2 * t + 1];
        p_tile[w][1][lane]      = s[1][2 * t];
        p_tile[w][1][64 + lane] = s[1][2 * t + 1];
        __syncthreads();

        #pragma unroll 1
        for (int m0 = 0; m0 < TK; m0 += 16) {
            const float4 p0 = *(const float4*)&p_tile[w][0][m0 + 4 * msub];
            const float4 p1 = *(const float4*)&p_tile[w][1][m0 + 4 * msub];
            const float* pf0 = (const float*)&p0;
            const float* pf1 = (const float*)&p1;
            #pragma unroll
            for (int c = 0; c < 4; ++c) {
                const float4 vv = *(const float4*)&smem[(m0 + 4 * msub + c) * PADK + 4 * d4];
                acc0.x += pf0[c] * vv.x;  acc0.y += pf0[c] * vv.y;
                acc0.z += pf0[c] * vv.z;  acc0.w += pf0[c] * vv.w;
                acc1.x += pf1[c] * vv.x;  acc1.y += pf1[c] * vv.y;
                acc1.z += pf1[c] * vv.z;  acc1.w += pf1[c] * vv.w;
            }
        }
    }

    // reduce partials across msub groups (butterfly over lane bits 4,5)
    #pragma unroll
    for (int off = 16; off <= 32; off <<= 1) {
        acc0.x += __shfl_xor(acc0.x, off, 64);
        acc0.y += __shfl_xor(acc0.y, off, 64);
        acc0.z += __shfl_xor(acc0.z, off, 64);
        acc0.w += __shfl_xor(acc0.w, off, 64);
        acc1.x += __shfl_xor(acc1.x, off, 64);
        acc1.y += __shfl_xor(acc1.y, off, 64);
        acc1.z += __shfl_xor(acc1.z, off, 64);
        acc1.w += __shfl_xor(acc1.w, off, 64);
    }
    if (msub == 0) {
        const int na = n0 + 2 * w;
        *(float4*)(Out + ((size_t)b * NSEQ + na) * DHEAD + 4 * d4)     = acc0;
        *(float4*)(Out + ((size_t)b * NSEQ + na + 1) * DHEAD + 4 * d4) = acc1;
    }
}

extern "C" void kernel_launch(void* const* d_in, const int* in_sizes, int n_in,
                              void* d_out, int out_size, void* d_ws, size_t ws_size,
                              hipStream_t stream) {
    const float* q = (const float*)d_in[0];
    const float* k = (const float*)d_in[1];
    const float* v = (const float*)d_in[2];
    float* out = (float*)d_out;
    (void)in_sizes; (void)n_in; (void)out_size; (void)d_ws; (void)ws_size;
    dim3 grid(4096), block(256);
    hipLaunchKernelGGL(entmax_attn_kernel, grid, block, 0, stream, q, k, v, out);
}

// Round 4
// 822.041 us; speedup vs baseline: 1.7910x; 1.7910x over previous
//
#include <hip/hip_runtime.h>

// Fused entmax(alpha=1.3) attention, fp32. B=16, N=2048, D=64.
// R4: occupancy/latency attack. PV back to global-V (L2-resident, zero
// barriers, no LDS conflicts); p hops through per-wave LDS in 2 segments so
// one V pass serves both q-rows. __launch_bounds__(256,4) caps VGPR at 128
// (16 waves/CU). Both rows' entmax solves interleaved (2x ILP on the serial
// bisection chain). 12 bisect + 2 Newton.

#define NBATCH 16
#define NSEQ   2048
#define DHEAD  64
#define OUT_OFF (NBATCH * NSEQ * DHEAD)   // out first, attn second
#define INV_A    3.3333333f               // 1/(alpha-1)
#define INV_A_M1 2.3333333f               // INV_A - 1
#define TK    128                         // K tile rows
#define PADK  68                          // LDS row stride: 272 B (R2: 0 conflicts)
#define NTILE (NSEQ / TK)                 // 16

__device__ __forceinline__ float fast_log2(float x) { return __builtin_amdgcn_logf(x); }
__device__ __forceinline__ float fast_exp2(float x) { return __builtin_amdgcn_exp2f(x); }

__global__ __launch_bounds__(256, 4) void entmax_attn_kernel(
    const float* __restrict__ Q, const float* __restrict__ K,
    const float* __restrict__ V, float* __restrict__ Out)
{
    // 8704 floats: K tiles in phase 1; per-wave p segments (4 x 2048) in PV
    __shared__ __align__(16) float smem[TK * PADK];
    __shared__ __align__(16) float q_lds[8][DHEAD];

    const int tid  = threadIdx.x;
    const int w    = tid >> 6;        // wave 0..3
    const int lane = tid & 63;

    // XCD pinning: batch b -> XCD b%8; K+V of 2 batches = 2 MB in 4 MB L2
    const int i   = blockIdx.x;       // 0..4095
    const int xcd = i & 7;
    const int j2  = i >> 3;
    const int b   = xcd + 8 * (j2 & 1);
    const int rb  = j2 >> 1;          // 0..255
    const int n0  = rb * 8;           // block covers q rows n0..n0+7

    const float* Kb = K + (size_t)b * NSEQ * DHEAD;
    const float* Vb = V + (size_t)b * NSEQ * DHEAD;

    if (tid < 128) {
        const int r = tid >> 4, g = tid & 15;
        ((float4*)q_lds[r])[g] =
            ((const float4*)(Q + ((size_t)b * NSEQ + (size_t)(n0 + r)) * DHEAD))[g];
    }

    // scores: s0/s1 for q-rows n0+2w / n0+2w+1; element m = j*64+lane.
    // all indices compile-time -> VGPR-resident (no scratch).
    float s0[32], s1[32];
    const float* q0p = q_lds[2 * w + 0];
    const float* q1p = q_lds[2 * w + 1];

    // ---------------- phase 1: QK^T, K tiled through LDS ----------------
    #pragma unroll
    for (int t = 0; t < NTILE; ++t) {
        __syncthreads();   // prev tile consumed (t=0: covers q staging)
        #pragma unroll 4
        for (int rep = 0; rep < 8; ++rep) {
            const int f = tid + rep * 256;
            const int m = f >> 4, g = f & 15;
            const float4 kv = ((const float4*)(Kb + (size_t)(t * TK + m) * DHEAD))[g];
            *(float4*)&smem[m * PADK + 4 * g] = kv;
        }
        __syncthreads();

        float a00 = 0.f, a01 = 0.f, a10 = 0.f, a11 = 0.f;
        #pragma unroll 1   // rolled: q from LDS broadcast each g, low VGPR
        for (int g = 0; g < 16; ++g) {
            const float4 k0 = *(const float4*)&smem[lane * PADK + 4 * g];
            const float4 k1 = *(const float4*)&smem[(64 + lane) * PADK + 4 * g];
            const float4 qa = *(const float4*)&q0p[4 * g];
            const float4 qb = *(const float4*)&q1p[4 * g];
            a00 += qa.x*k0.x + qa.y*k0.y + qa.z*k0.z + qa.w*k0.w;
            a01 += qa.x*k1.x + qa.y*k1.y + qa.z*k1.z + qa.w*k1.w;
            a10 += qb.x*k0.x + qb.y*k0.y + qb.z*k0.z + qb.w*k0.w;
            a11 += qb.x*k1.x + qb.y*k1.y + qb.z*k1.z + qb.w*k1.w;
        }
        s0[2*t]   = a00 * 0.125f;
        s0[2*t+1] = a01 * 0.125f;
        s1[2*t]   = a10 * 0.125f;
        s1[2*t+1] = a11 * 0.125f;
    }
    __syncthreads();   // all K reads done; smem region becomes per-wave p space

    // ---------------- phase 2: entmax, both rows interleaved ----------------
    float mxa = s0[0], mxb = s1[0];
    #pragma unroll
    for (int j = 1; j < 32; ++j) { mxa = fmaxf(mxa, s0[j]); mxb = fmaxf(mxb, s1[j]); }
    #pragma unroll
    for (int off = 32; off >= 1; off >>= 1) {
        mxa = fmaxf(mxa, __shfl_xor(mxa, off, 64));
        mxb = fmaxf(mxb, __shfl_xor(mxb, off, 64));
    }
    #pragma unroll
    for (int j = 0; j < 32; ++j) { s0[j] -= mxa; s1[j] -= mxb; }

    // bisection: root of sum(max(x-tau,0)^INV_A) = 1 in [-1, -1e-6]
    float loa = -1.f, hia = -1e-6f, lob = -1.f, hib = -1e-6f;
    #pragma unroll 1
    for (int it = 0; it < 12; ++it) {
        const float ta = 0.5f * (loa + hia);
        const float tb = 0.5f * (lob + hib);
        float Sa = 0.f, Sb = 0.f;
        #pragma unroll
        for (int j = 0; j < 32; ++j) {
            const float t0 = s0[j] - ta;
            const float t1 = s1[j] - tb;
            const float p0 = fast_exp2(INV_A * fast_log2(t0));
            const float p1 = fast_exp2(INV_A * fast_log2(t1));
            Sa += (t0 > 0.f) ? p0 : 0.f;
            Sb += (t1 > 0.f) ? p1 : 0.f;
        }
        #pragma unroll
        for (int off = 32; off >= 1; off >>= 1) {
            Sa += __shfl_xor(Sa, off, 64);
            Sb += __shfl_xor(Sb, off, 64);
        }
        if (Sa > 1.f) loa = ta; else hia = ta;   // wave-uniform
        if (Sb > 1.f) lob = tb; else hib = tb;
    }

    // Newton polish from left brackets (clamped, monotone-safe)
    float taua = loa, taub = lob;
    #pragma unroll 1
    for (int it = 0; it < 2; ++it) {
        float S1a = 0.f, S2a = 0.f, S1b = 0.f, S2b = 0.f;
        #pragma unroll
        for (int j = 0; j < 32; ++j) {
            const float t0 = s0[j] - taua;
            const float t1 = s1[j] - taub;
            const float l0 = fast_log2(t0);
            const float l1 = fast_log2(t1);
            const float p0 = fast_exp2(INV_A * l0);
            const float p1 = fast_exp2(INV_A * l1);
            const float d0 = fast_exp2(INV_A_M1 * l0);
            const float d1 = fast_exp2(INV_A_M1 * l1);
            const bool g0 = t0 > 0.f, g1 = t1 > 0.f;
            S1a += g0 ? p0 : 0.f;  S2a += g0 ? d0 : 0.f;
            S1b += g1 ? p1 : 0.f;  S2b += g1 ? d1 : 0.f;
        }
        #pragma unroll
        for (int off = 32; off >= 1; off >>= 1) {
            S1a += __shfl_xor(S1a, off, 64);
            S2a += __shfl_xor(S2a, off, 64);
            S1b += __shfl_xor(S1b, off, 64);
            S2b += __shfl_xor(S2b, off, 64);
        }
        taua += (S1a - 1.f) / (INV_A * S2a);
        taub += (S1b - 1.f) / (INV_A * S2b);
        taua = fmaxf(fminf(taua, hia), loa);
        taub = fmaxf(fminf(taub, hib), lob);
    }

    // final p + sums (interleaved)
    float Sa = 0.f, Sb = 0.f;
    #pragma unroll
    for (int j = 0; j < 32; ++j) {
        const float t0 = s0[j] - taua;
        const float t1 = s1[j] - taub;
        const float p0 = (t0 > 0.f) ? fast_exp2(INV_A * fast_log2(t0)) : 0.f;
        const float p1 = (t1 > 0.f) ? fast_exp2(INV_A * fast_log2(t1)) : 0.f;
        s0[j] = p0; s1[j] = p1;
        Sa += p0; Sb += p1;
    }
    #pragma unroll
    for (int off = 32; off >= 1; off >>= 1) {
        Sa += __shfl_xor(Sa, off, 64);
        Sb += __shfl_xor(Sb, off, 64);
    }
    const float ran = 1.f / (Sa + 1e-12f);
    const float rbn = 1.f / (Sb + 1e-12f);

    // normalize + non-temporal attn writes (268 MB stream stays out of L2)
    const int na = n0 + 2 * w;
    float* attn0 = Out + OUT_OFF + ((size_t)b * NSEQ + na) * NSEQ;
    float* attn1 = attn0 + NSEQ;
    #pragma unroll
    for (int j = 0; j < 32; ++j) {
        s0[j] *= ran;  s1[j] *= rbn;
        __builtin_nontemporal_store(s0[j], &attn0[j * 64 + lane]);
        __builtin_nontemporal_store(s1[j], &attn1[j * 64 + lane]);
    }

    // ---------------- phase 3: PV, V from global (L2), p via per-wave LDS ---
    // wave-private region smem[w*2048 .. +2048): seg layout [row0 1024 | row1 1024]
    float* pw = &smem[w * 2048];
    const int msub = lane >> 4;
    const int d4   = lane & 15;
    float4 acc0 = make_float4(0.f, 0.f, 0.f, 0.f);
    float4 acc1 = make_float4(0.f, 0.f, 0.f, 0.f);

    #pragma unroll
    for (int seg = 0; seg < 2; ++seg) {
        #pragma unroll
        for (int jj = 0; jj < 16; ++jj) {       // same-wave RAW, no barrier
            pw[jj * 64 + lane]        = s0[seg * 16 + jj];
            pw[1024 + jj * 64 + lane] = s1[seg * 16 + jj];
        }
        #pragma unroll 2
        for (int m0 = 0; m0 < 1024; m0 += 16) {
            const float4 p0 = *(const float4*)&pw[m0 + 4 * msub];          // broadcast
            const float4 p1 = *(const float4*)&pw[1024 + m0 + 4 * msub];   // broadcast
            const float* pf0 = (const float*)&p0;
            const float* pf1 = (const float*)&p1;
            #pragma unroll
            for (int c = 0; c < 4; ++c) {
                const float4 vv = *(const float4*)(
                    Vb + (size_t)(seg * 1024 + m0 + 4 * msub + c) * DHEAD + 4 * d4);
                acc0.x += pf0[c] * vv.x;  acc0.y += pf0[c] * vv.y;
                acc0.z += pf0[c] * vv.z;  acc0.w += pf0[c] * vv.w;
                acc1.x += pf1[c] * vv.x;  acc1.y += pf1[c] * vv.y;
                acc1.z += pf1[c] * vv.z;  acc1.w += pf1[c] * vv.w;
            }
        }
    }

    #pragma unroll
    for (int off = 16; off <= 32; off <<= 1) {
        acc0.x += __shfl_xor(acc0.x, off, 64);
        acc0.y += __shfl_xor(acc0.y, off, 64);
        acc0.z += __shfl_xor(acc0.z, off, 64);
        acc0.w += __shfl_xor(acc0.w, off, 64);
        acc1.x += __shfl_xor(acc1.x, off, 64);
        acc1.y += __shfl_xor(acc1.y, off, 64);
        acc1.z += __shfl_xor(acc1.z, off, 64);
        acc1.w += __shfl_xor(acc1.w, off, 64);
    }
    if (msub == 0) {
        *(float4*)(Out + ((size_t)b * NSEQ + na) * DHEAD + 4 * d4)     = acc0;
        *(float4*)(Out + ((size_t)b * NSEQ + na + 1) * DHEAD + 4 * d4) = acc1;
    }
}

extern "C" void kernel_launch(void* const* d_in, const int* in_sizes, int n_in,
                              void* d_out, int out_size, void* d_ws, size_t ws_size,
                              hipStream_t stream) {
    const float* q = (const float*)d_in[0];
    const float* k = (const float*)d_in[1];
    const float* v = (const float*)d_in[2];
    float* out = (float*)d_out;
    (void)in_sizes; (void)n_in; (void)out_size; (void)d_ws; (void)ws_size;
    dim3 grid(4096), block(256);
    hipLaunchKernelGGL(entmax_attn_kernel, grid, block, 0, stream, q, k, v, out);
}

// Round 5
// 565.818 us; speedup vs baseline: 2.6021x; 1.4528x over previous
//
#include <hip/hip_runtime.h>

// Fused entmax(alpha=1.3) attention, fp32. B=16, N=2048, D=64.
// R5: sparsity exploit. entmax support = elements > rowmax-1 (provable:
// tau* >= max-1), typically ~10-40 of 2048. Ballot-compact the active set
// once, run all bisection/Newton sweeps on <=2 compact regs/lane (trans
// work /32), write attn row as zeros + scatter, sparse PV over only the
// active V rows (~25 instead of 2048). A>128 -> dense fallback (rare,
// wave-uniform). No forced waves/EU bound (caused R2/R4 spills); score
// regs die at compaction so natural pressure ~110.

#define NBATCH 16
#define NSEQ   2048
#define DHEAD  64
#define OUT_OFF (NBATCH * NSEQ * DHEAD)   // out first, attn second
#define INV_A    3.3333333f               // 1/(alpha-1)
#define INV_A_M1 2.3333333f
#define TK    128
#define PADK  68                          // K-tile LDS row stride (0 conflicts, R2)
#define NTILE (NSEQ / TK)                 // 16
#define WREG  2176                        // per-wave float region: TK*PADK/4

__device__ __forceinline__ float fast_log2(float x) { return __builtin_amdgcn_logf(x); }
__device__ __forceinline__ float fast_exp2(float x) { return __builtin_amdgcn_exp2f(x); }

__global__ __launch_bounds__(256) void entmax_attn_kernel(
    const float* __restrict__ Q, const float* __restrict__ K,
    const float* __restrict__ V, float* __restrict__ Out)
{
    // phase 1: K tiles (128 x 68). phase 2/3: per-wave regions of 2176 floats:
    //   [0..1024)    prow   — one 1024-float attn segment buffer
    //   [1024..1152) cval   — compact values, then normalized p
    //   [1152..1280) cidx   — compact indices (stored as float, exact < 2048)
    __shared__ __align__(16) float smem[TK * PADK];
    __shared__ __align__(16) float q_lds[8][DHEAD];

    const int tid  = threadIdx.x;
    const int w    = tid >> 6;
    const int lane = tid & 63;

    // XCD pinning: batch b -> XCD b%8; K+V of 2 batches = 2 MB in 4 MB L2
    const int i   = blockIdx.x;       // 0..4095
    const int xcd = i & 7;
    const int j2  = i >> 3;
    const int b   = xcd + 8 * (j2 & 1);
    const int rb  = j2 >> 1;          // 0..255
    const int n0  = rb * 8;

    const float* Kb = K + (size_t)b * NSEQ * DHEAD;
    const float* Vb = V + (size_t)b * NSEQ * DHEAD;

    if (tid < 128) {
        const int r = tid >> 4, g = tid & 15;
        ((float4*)q_lds[r])[g] =
            ((const float4*)(Q + ((size_t)b * NSEQ + (size_t)(n0 + r)) * DHEAD))[g];
    }

    // scores s[r][j]: q-row n0+2w+r vs key m = j*64+lane. compile-time indices only.
    float s[2][32];
    const float* q0p = q_lds[2 * w + 0];
    const float* q1p = q_lds[2 * w + 1];

    // ---------------- phase 1: QK^T, K tiled through LDS ----------------
    #pragma unroll
    for (int t = 0; t < NTILE; ++t) {
        __syncthreads();
        #pragma unroll 4
        for (int rep = 0; rep < 8; ++rep) {
            const int f = tid + rep * 256;
            const int m = f >> 4, g = f & 15;
            const float4 kv = ((const float4*)(Kb + (size_t)(t * TK + m) * DHEAD))[g];
            *(float4*)&smem[m * PADK + 4 * g] = kv;
        }
        __syncthreads();

        float a00 = 0.f, a01 = 0.f, a10 = 0.f, a11 = 0.f;
        #pragma unroll 1
        for (int g = 0; g < 16; ++g) {
            const float4 k0 = *(const float4*)&smem[lane * PADK + 4 * g];
            const float4 k1 = *(const float4*)&smem[(64 + lane) * PADK + 4 * g];
            const float4 qa = *(const float4*)&q0p[4 * g];
            const float4 qb = *(const float4*)&q1p[4 * g];
            a00 += qa.x*k0.x + qa.y*k0.y + qa.z*k0.z + qa.w*k0.w;
            a01 += qa.x*k1.x + qa.y*k1.y + qa.z*k1.z + qa.w*k1.w;
            a10 += qb.x*k0.x + qb.y*k0.y + qb.z*k0.z + qb.w*k0.w;
            a11 += qb.x*k1.x + qb.y*k1.y + qb.z*k1.z + qb.w*k1.w;
        }
        s[0][2*t]   = a00 * 0.125f;
        s[0][2*t+1] = a01 * 0.125f;
        s[1][2*t]   = a10 * 0.125f;
        s[1][2*t+1] = a11 * 0.125f;
    }
    __syncthreads();   // all K reads done; smem becomes per-wave regions

    float* wreg = &smem[w * WREG];
    float* prow = wreg;
    float* cval = wreg + 1024;
    float* cidx = wreg + 1152;
    const unsigned long long lt_mask = (1ull << lane) - 1ull;
    const int na = n0 + 2 * w;

    #pragma unroll
    for (int r = 0; r < 2; ++r) {
        // row max (butterfly -> identical in all lanes)
        float mx = s[r][0];
        #pragma unroll
        for (int j = 1; j < 32; ++j) mx = fmaxf(mx, s[r][j]);
        #pragma unroll
        for (int off = 32; off >= 1; off >>= 1) mx = fmaxf(mx, __shfl_xor(mx, off, 64));
        #pragma unroll
        for (int j = 0; j < 32; ++j) s[r][j] -= mx;

        // ballot-compact elements > -1 (only these can be in the support)
        int base = 0;
        #pragma unroll
        for (int j = 0; j < 32; ++j) {
            const bool act = s[r][j] > -1.0f;
            const unsigned long long bm = __ballot(act);
            const int pos = base + __popcll(bm & lt_mask);
            if (act && pos < 128) {
                cval[pos] = s[r][j];
                cidx[pos] = (float)(j * 64 + lane);
            }
            base += __popcll(bm);
        }
        const int A = base;               // wave-uniform
        float outacc = 0.f;

        if (A <= 128) {
            // -------- sparse solver on <=2 compact elements per lane --------
            const float cv0 = cval[lane];
            const float cv1 = cval[64 + lane];
            const bool ok0 = (lane < A);
            const bool ok1 = (64 + lane < A);

            float lo = -1.0f, hi = -1e-6f;
            #pragma unroll 1
            for (int it = 0; it < 12; ++it) {
                const float tau = 0.5f * (lo + hi);
                const float t0 = cv0 - tau, t1 = cv1 - tau;
                float S = ((ok0 && t0 > 0.f) ? fast_exp2(INV_A * fast_log2(t0)) : 0.f)
                        + ((ok1 && t1 > 0.f) ? fast_exp2(INV_A * fast_log2(t1)) : 0.f);
                #pragma unroll
                for (int off = 32; off >= 1; off >>= 1) S += __shfl_xor(S, off, 64);
                if (S > 1.f) lo = tau; else hi = tau;
            }
            float tau = lo;
            #pragma unroll 1
            for (int it = 0; it < 2; ++it) {
                const float t0 = cv0 - tau, t1 = cv1 - tau;
                float S1 = 0.f, S2 = 0.f;
                if (ok0 && t0 > 0.f) {
                    const float l = fast_log2(t0);
                    S1 += fast_exp2(INV_A * l); S2 += fast_exp2(INV_A_M1 * l);
                }
                if (ok1 && t1 > 0.f) {
                    const float l = fast_log2(t1);
                    S1 += fast_exp2(INV_A * l); S2 += fast_exp2(INV_A_M1 * l);
                }
                #pragma unroll
                for (int off = 32; off >= 1; off >>= 1) {
                    S1 += __shfl_xor(S1, off, 64);
                    S2 += __shfl_xor(S2, off, 64);
                }
                tau += (S1 - 1.f) / (INV_A * S2);
                tau = fmaxf(fminf(tau, hi), lo);
            }

            // final p on the compact set + normalize
            const float t0 = cv0 - tau, t1 = cv1 - tau;
            float p0 = (ok0 && t0 > 0.f) ? fast_exp2(INV_A * fast_log2(t0)) : 0.f;
            float p1 = (ok1 && t1 > 0.f) ? fast_exp2(INV_A * fast_log2(t1)) : 0.f;
            float S = p0 + p1;
            #pragma unroll
            for (int off = 32; off >= 1; off >>= 1) S += __shfl_xor(S, off, 64);
            const float rnorm = 1.f / (S + 1e-12f);
            p0 *= rnorm; p1 *= rnorm;
            const int i0 = ok0 ? (int)cidx[lane] : 0;
            const int i1 = ok1 ? (int)cidx[64 + lane] : 0;
            if (ok0) cval[lane] = p0;        // cval now holds normalized p
            if (ok1) cval[64 + lane] = p1;

            // -------- attn row: zeros + scatter, two 1024-float segments ----
            float* arow = Out + OUT_OFF + ((size_t)b * NSEQ + (na + r)) * NSEQ;
            #pragma unroll
            for (int seg = 0; seg < 2; ++seg) {
                #pragma unroll
                for (int z = 0; z < 4; ++z)
                    *(float4*)&prow[(z * 64 + lane) * 4] = make_float4(0.f, 0.f, 0.f, 0.f);
                if (ok0 && (i0 >> 10) == seg) prow[i0 & 1023] = p0;
                if (ok1 && (i1 >> 10) == seg) prow[i1 & 1023] = p1;
                #pragma unroll
                for (int z = 0; z < 16; ++z)
                    __builtin_nontemporal_store(prow[z * 64 + lane],
                                                &arow[seg * 1024 + z * 64 + lane]);
            }

            // -------- sparse PV: only active V rows; out dim d = lane --------
            int ii = 0;
            #pragma unroll 1
            for (; ii + 4 <= A; ii += 4) {
                const float pa = cval[ii + 0], pb = cval[ii + 1];
                const float pc = cval[ii + 2], pd = cval[ii + 3];
                const int ma = (int)cidx[ii + 0], mb = (int)cidx[ii + 1];
                const int mc = (int)cidx[ii + 2], md = (int)cidx[ii + 3];
                const float va = Vb[(size_t)ma * DHEAD + lane];
                const float vb2 = Vb[(size_t)mb * DHEAD + lane];
                const float vc = Vb[(size_t)mc * DHEAD + lane];
                const float vd = Vb[(size_t)md * DHEAD + lane];
                outacc += pa * va + pb * vb2 + pc * vc + pd * vd;
            }
            #pragma unroll 1
            for (; ii < A; ++ii)
                outacc += cval[ii] * Vb[(size_t)(int)cidx[ii] * DHEAD + lane];
        } else {
            // -------- dense fallback (rare; correctness path) ---------------
            float lo = -1.0f, hi = -1e-6f;
            #pragma unroll 1
            for (int it = 0; it < 12; ++it) {
                const float tau = 0.5f * (lo + hi);
                float S = 0.f;
                #pragma unroll
                for (int j = 0; j < 32; ++j) {
                    const float t = s[r][j] - tau;
                    const float p = fast_exp2(INV_A * fast_log2(t));
                    S += (t > 0.f) ? p : 0.f;
                }
                #pragma unroll
                for (int off = 32; off >= 1; off >>= 1) S += __shfl_xor(S, off, 64);
                if (S > 1.f) lo = tau; else hi = tau;
            }
            float tau = lo;
            #pragma unroll 1
            for (int it = 0; it < 2; ++it) {
                float S1 = 0.f, S2 = 0.f;
                #pragma unroll
                for (int j = 0; j < 32; ++j) {
                    const float t = s[r][j] - tau;
                    if (t > 0.f) {
                        const float l = fast_log2(t);
                        S1 += fast_exp2(INV_A * l); S2 += fast_exp2(INV_A_M1 * l);
                    }
                }
                #pragma unroll
                for (int off = 32; off >= 1; off >>= 1) {
                    S1 += __shfl_xor(S1, off, 64);
                    S2 += __shfl_xor(S2, off, 64);
                }
                tau += (S1 - 1.f) / (INV_A * S2);
                tau = fmaxf(fminf(tau, hi), lo);
            }
            float S = 0.f;
            #pragma unroll
            for (int j = 0; j < 32; ++j) {
                const float t = s[r][j] - tau;
                const float p = (t > 0.f) ? fast_exp2(INV_A * fast_log2(t)) : 0.f;
                s[r][j] = p;
                S += p;
            }
            #pragma unroll
            for (int off = 32; off >= 1; off >>= 1) S += __shfl_xor(S, off, 64);
            const float rnorm = 1.f / (S + 1e-12f);

            float* arow = Out + OUT_OFF + ((size_t)b * NSEQ + (na + r)) * NSEQ;
            #pragma unroll
            for (int seg = 0; seg < 2; ++seg) {
                #pragma unroll
                for (int jj = 0; jj < 16; ++jj)
                    prow[jj * 64 + lane] = s[r][seg * 16 + jj] * rnorm;
                #pragma unroll
                for (int z = 0; z < 16; ++z)
                    __builtin_nontemporal_store(prow[z * 64 + lane],
                                                &arow[seg * 1024 + z * 64 + lane]);
                #pragma unroll 4
                for (int m = 0; m < 1024; ++m)
                    outacc += prow[m] * Vb[(size_t)(seg * 1024 + m) * DHEAD + lane];
            }
        }

        Out[((size_t)b * NSEQ + (na + r)) * DHEAD + lane] = outacc;
    }
}

extern "C" void kernel_launch(void* const* d_in, const int* in_sizes, int n_in,
                              void* d_out, int out_size, void* d_ws, size_t ws_size,
                              hipStream_t stream) {
    const float* q = (const float*)d_in[0];
    const float* k = (const float*)d_in[1];
    const float* v = (const float*)d_in[2];
    float* out = (float*)d_out;
    (void)in_sizes; (void)n_in; (void)out_size; (void)d_ws; (void)ws_size;
    dim3 grid(4096), block(256);
    hipLaunchKernelGGL(entmax_attn_kernel, grid, block, 0, stream, q, k, v, out);
}